// Round 1
// baseline (310.764 us; speedup 1.0000x reference)
//
#include <hip/hip_runtime.h>
#include <math.h>

#define B_ 4
#define T_ 4096
#define D_ 2048
#define CT 32
#define NC (T_ / CT)   // 128 chunks

// tanh(u) = 1 - 2/(exp(2u)+1); v_exp-based, handles +-inf saturation correctly
__device__ __forceinline__ float fast_tanh(float u) {
    float e = __expf(2.0f * u);
    return 1.0f - 2.0f / (e + 1.0f);
}

__device__ __forceinline__ float gelu_tanh(float x) {
    const float c = 0.7978845608028654f;  // sqrt(2/pi)
    float u = c * (x + 0.044715f * x * x * x);
    return 0.5f * x * (1.0f + fast_tanh(u));
}

// K1: per (b, chunk) compute chunk-local sums of x, x^2, gelu(x) per channel.
__global__ __launch_bounds__(256) void k1_partials(
        const float* __restrict__ x,
        float* __restrict__ px, float* __restrict__ pxx, float* __restrict__ po) {
    int bid = blockIdx.x;
    int b = bid / NC, c = bid % NC;
    int tid = threadIdx.x;
    int d0 = tid * 8;                     // 8 contiguous channels per thread
    float sx[8], sxx[8], so[8];
#pragma unroll
    for (int i = 0; i < 8; i++) { sx[i] = 0.f; sxx[i] = 0.f; so[i] = 0.f; }

    const float* base = x + ((size_t)(b * T_ + c * CT)) * D_ + d0;
    for (int t = 0; t < CT; t++) {
        float4 v0 = *(const float4*)(base);
        float4 v1 = *(const float4*)(base + 4);
        float v[8] = {v0.x, v0.y, v0.z, v0.w, v1.x, v1.y, v1.z, v1.w};
#pragma unroll
        for (int i = 0; i < 8; i++) {
            sx[i]  += v[i];
            sxx[i] += v[i] * v[i];
            so[i]  += gelu_tanh(v[i]);
        }
        base += D_;
    }
    size_t pidx = (size_t)(b * NC + c) * D_ + d0;
    *(float4*)(px  + pidx)     = make_float4(sx[0], sx[1], sx[2], sx[3]);
    *(float4*)(px  + pidx + 4) = make_float4(sx[4], sx[5], sx[6], sx[7]);
    *(float4*)(pxx + pidx)     = make_float4(sxx[0], sxx[1], sxx[2], sxx[3]);
    *(float4*)(pxx + pidx + 4) = make_float4(sxx[4], sxx[5], sxx[6], sxx[7]);
    *(float4*)(po  + pidx)     = make_float4(so[0], so[1], so[2], so[3]);
    *(float4*)(po  + pidx + 4) = make_float4(so[4], so[5], so[6], so[7]);
}

// K2: exclusive scan over chunks per (b,d): partials -> chunk-prefix offsets.
__global__ __launch_bounds__(256) void k2_scan(
        float* __restrict__ px, float* __restrict__ pxx, float* __restrict__ po) {
    int gid = blockIdx.x * blockDim.x + threadIdx.x;   // 0 .. B*D-1
    int b = gid / D_, d = gid % D_;
    float rx = 0.f, rxx = 0.f, ro = 0.f;
    size_t idx = (size_t)b * NC * D_ + d;
    for (int c = 0; c < NC; c++) {
        float tx = px[idx], txx = pxx[idx], to = po[idx];
        px[idx] = rx; pxx[idx] = rxx; po[idx] = ro;
        rx += tx; rxx += txx; ro += to;
        idx += D_;
    }
}

// K3: per (b, chunk) serial walk over CT timesteps with running exclusive sums,
// block-reduce 4 scalars per step, apply gate, write output.
__global__ __launch_bounds__(256) void k3_main(
        const float* __restrict__ x,
        const float* __restrict__ px, const float* __restrict__ pxx,
        const float* __restrict__ po,
        const float* __restrict__ p_log_tau,
        const float* __restrict__ p_log_sigma_raw,
        const float* __restrict__ p_log_w_raw,
        float* __restrict__ y) {
    __shared__ float4 red[4];   // one float4 per wave (4 waves of 64)

    int bid = blockIdx.x;
    int b = bid / NC, c = bid % NC;
    int tid = threadIdx.x;
    int d0 = tid * 8;

    float tau   = __expf(p_log_tau[0]);
    float sigma = log1pf(__expf(p_log_sigma_raw[0]));   // softplus
    float w     = log1pf(__expf(p_log_w_raw[0]));

    // running exclusive sums, initialized from chunk offsets
    float cx[8], cxx[8], co[8];
    size_t pidx = (size_t)(b * NC + c) * D_ + d0;
    {
        float4 a0 = *(const float4*)(px  + pidx);
        float4 a1 = *(const float4*)(px  + pidx + 4);
        float4 b0 = *(const float4*)(pxx + pidx);
        float4 b1 = *(const float4*)(pxx + pidx + 4);
        float4 c0 = *(const float4*)(po  + pidx);
        float4 c1 = *(const float4*)(po  + pidx + 4);
        cx[0]=a0.x; cx[1]=a0.y; cx[2]=a0.z; cx[3]=a0.w;
        cx[4]=a1.x; cx[5]=a1.y; cx[6]=a1.z; cx[7]=a1.w;
        cxx[0]=b0.x; cxx[1]=b0.y; cxx[2]=b0.z; cxx[3]=b0.w;
        cxx[4]=b1.x; cxx[5]=b1.y; cxx[6]=b1.z; cxx[7]=b1.w;
        co[0]=c0.x; co[1]=c0.y; co[2]=c0.z; co[3]=c0.w;
        co[4]=c1.x; co[5]=c1.y; co[6]=c1.z; co[7]=c1.w;
    }

    const float* xb = x + ((size_t)(b * T_ + c * CT)) * D_ + d0;
    float*       yb = y + ((size_t)(b * T_ + c * CT)) * D_ + d0;

    for (int t = 0; t < CT; t++) {
        int tg = c * CT + t;            // global timestep, 0-based
        float nf = (float)(tg + 1);     // counts
        float inv = __builtin_amdgcn_rcpf(nf);

        float4 v0 = *(const float4*)(xb);
        float4 v1 = *(const float4*)(xb + 4);
        float v[8] = {v0.x, v0.y, v0.z, v0.w, v1.x, v1.y, v1.z, v1.w};

        float o[8];
        float a_absz = 0.f, a_dot = 0.f, a_no2 = 0.f, a_nm2 = 0.f;
#pragma unroll
        for (int i = 0; i < 8; i++) {
            float vv = v[i];
            float oo = gelu_tanh(vv);
            o[i] = oo;
            float mu  = cx[i]  * inv;
            float sq  = cxx[i] * inv;
            float var = fmaxf(sq - mu * mu, 1e-4f);
            float stde = __builtin_amdgcn_sqrtf(var) + 1e-5f;
            float z = (vv - mu) * __builtin_amdgcn_rcpf(stde);
            a_absz += fabsf(z);
            float mo = co[i] * inv;
            a_dot += oo * mo;
            a_no2 += oo * oo;
            a_nm2 += mo * mo;
            cx[i]  += vv;
            cxx[i] += vv * vv;
            co[i]  += oo;
        }

        // wave-level reduce (64 lanes)
#pragma unroll
        for (int off = 32; off >= 1; off >>= 1) {
            a_absz += __shfl_down(a_absz, off);
            a_dot  += __shfl_down(a_dot,  off);
            a_no2  += __shfl_down(a_no2,  off);
            a_nm2  += __shfl_down(a_nm2,  off);
        }
        int wid = tid >> 6;
        __syncthreads();   // protect red[] from previous iteration's readers
        if ((tid & 63) == 0) red[wid] = make_float4(a_absz, a_dot, a_no2, a_nm2);
        __syncthreads();
        float s_absz = 0.f, s_dot = 0.f, s_no2 = 0.f, s_nm2 = 0.f;
#pragma unroll
        for (int k = 0; k < 4; k++) {
            float4 r = red[k];
            s_absz += r.x; s_dot += r.y; s_no2 += r.z; s_nm2 += r.w;
        }

        float mask = (tg >= 1) ? 1.0f : 0.0f;       // counts > 1
        float mabs = s_absz * (1.0f / (float)D_) * mask;
        float denom = fmaxf(sqrtf(s_no2), 1e-12f) * fmaxf(sqrtf(s_nm2), 1e-12f);
        float cosv = (s_dot / denom) * mask;
        float gate = __expf(-tau * cosv) * (1.0f + w * fast_tanh(sigma * mabs));

        *(float4*)(yb)     = make_float4(o[0]*gate, o[1]*gate, o[2]*gate, o[3]*gate);
        *(float4*)(yb + 4) = make_float4(o[4]*gate, o[5]*gate, o[6]*gate, o[7]*gate);

        xb += D_; yb += D_;
    }
}

extern "C" void kernel_launch(void* const* d_in, const int* in_sizes, int n_in,
                              void* d_out, int out_size, void* d_ws, size_t ws_size,
                              hipStream_t stream) {
    const float* x   = (const float*)d_in[0];
    const float* lt  = (const float*)d_in[1];
    const float* lsr = (const float*)d_in[2];
    const float* lwr = (const float*)d_in[3];
    float* y = (float*)d_out;

    const size_t npart = (size_t)B_ * NC * D_;   // 1,048,576 floats per array
    float* px  = (float*)d_ws;
    float* pxx = px  + npart;
    float* po  = pxx + npart;
    // requires 3 * npart * 4 = 12.6 MiB of workspace

    k1_partials<<<B_ * NC, 256, 0, stream>>>(x, px, pxx, po);
    k2_scan<<<(B_ * D_) / 256, 256, 0, stream>>>(px, pxx, po);
    k3_main<<<B_ * NC, 256, 0, stream>>>(x, px, pxx, po, lt, lsr, lwr, y);
}

// Round 2
// 285.438 us; speedup vs baseline: 1.0887x; 1.0887x over previous
//
#include <hip/hip_runtime.h>
#include <math.h>

#define B_ 4
#define T_ 4096
#define D_ 2048
#define CT 32
#define NC (T_ / CT)      // 128 chunks
#define NG 8              // scan groups per (b,d) channel
#define GC (NC / NG)      // 16 chunks per group

__device__ __forceinline__ float fast_rcp(float x) { return __builtin_amdgcn_rcpf(x); }

// tanh(u) = 1 - 2/(e^{2u}+1), div replaced by v_rcp
__device__ __forceinline__ float fast_tanh(float u) {
    float e = __expf(2.0f * u);
    return 1.0f - 2.0f * fast_rcp(e + 1.0f);
}

// 0.5*x*(1+tanh(u)) == x - x/(exp(2u)+1)  -> 1 exp + 1 rcp + few fma
__device__ __forceinline__ float gelu_tanh(float x) {
    const float c = 0.7978845608028654f;  // sqrt(2/pi)
    float u = c * x * fmaf(0.044715f, x * x, 1.0f);
    float e = __expf(2.0f * u);
    return x - x * fast_rcp(e + 1.0f);
}

// K1: per (b, chunk) chunk-local sums of x, x^2, gelu(x) per channel.
__global__ __launch_bounds__(256) void k1_partials(
        const float* __restrict__ x,
        float* __restrict__ px, float* __restrict__ pxx, float* __restrict__ po) {
    int bid = blockIdx.x;
    int b = bid / NC, c = bid % NC;
    int tid = threadIdx.x;
    int d0 = tid * 8;
    float sx[8], sxx[8], so[8];
#pragma unroll
    for (int i = 0; i < 8; i++) { sx[i] = 0.f; sxx[i] = 0.f; so[i] = 0.f; }

    const float* base = x + ((size_t)(b * T_ + c * CT)) * D_ + d0;
    for (int t = 0; t < CT; t++) {
        float4 v0 = *(const float4*)(base);
        float4 v1 = *(const float4*)(base + 4);
        float v[8] = {v0.x, v0.y, v0.z, v0.w, v1.x, v1.y, v1.z, v1.w};
#pragma unroll
        for (int i = 0; i < 8; i++) {
            sx[i]  += v[i];
            sxx[i]  = fmaf(v[i], v[i], sxx[i]);
            so[i]  += gelu_tanh(v[i]);
        }
        base += D_;
    }
    size_t pidx = (size_t)(b * NC + c) * D_ + d0;
    *(float4*)(px  + pidx)     = make_float4(sx[0], sx[1], sx[2], sx[3]);
    *(float4*)(px  + pidx + 4) = make_float4(sx[4], sx[5], sx[6], sx[7]);
    *(float4*)(pxx + pidx)     = make_float4(sxx[0], sxx[1], sxx[2], sxx[3]);
    *(float4*)(pxx + pidx + 4) = make_float4(sxx[4], sxx[5], sxx[6], sxx[7]);
    *(float4*)(po  + pidx)     = make_float4(so[0], so[1], so[2], so[3]);
    *(float4*)(po  + pidx + 4) = make_float4(so[4], so[5], so[6], so[7]);
}

// K2a: per (b, group, d) sum the group's 16 chunk-partials (independent,
// pipelined loads) -> group totals. 65536 threads = 256 blocks.
__global__ __launch_bounds__(256) void k2a_group_sums(
        const float* __restrict__ px, const float* __restrict__ pxx,
        const float* __restrict__ po,
        float* __restrict__ gx, float* __restrict__ gxx, float* __restrict__ go) {
    int gid = blockIdx.x * 256 + threadIdx.x;
    int d = gid & (D_ - 1);
    int g = (gid >> 11) & (NG - 1);
    int b = gid >> 14;
    size_t base = ((size_t)(b * NC + g * GC)) * D_ + d;
    float sx = 0.f, sxx = 0.f, so = 0.f;
#pragma unroll
    for (int j = 0; j < GC; j++) {
        sx  += px [base + (size_t)j * D_];
        sxx += pxx[base + (size_t)j * D_];
        so  += po [base + (size_t)j * D_];
    }
    size_t gi = ((size_t)(b * NG + g)) * D_ + d;
    gx[gi] = sx; gxx[gi] = sxx; go[gi] = so;
}

// K2c: per (b, group, d): exclusive offset from previous groups' totals
// (<=7 L2-hot loads), then serial in-place exclusive scan of the group's 16
// chunk partials. 65536 threads = 256 blocks.
__global__ __launch_bounds__(256) void k2c_scan(
        float* __restrict__ px, float* __restrict__ pxx, float* __restrict__ po,
        const float* __restrict__ gx, const float* __restrict__ gxx,
        const float* __restrict__ go) {
    int gid = blockIdx.x * 256 + threadIdx.x;
    int d = gid & (D_ - 1);
    int g = (gid >> 11) & (NG - 1);   // uniform within a block
    int b = gid >> 14;

    float ox = 0.f, oxx = 0.f, oo = 0.f;
    for (int g2 = 0; g2 < g; g2++) {
        size_t gi = ((size_t)(b * NG + g2)) * D_ + d;
        ox += gx[gi]; oxx += gxx[gi]; oo += go[gi];
    }
    size_t base = ((size_t)(b * NC + g * GC)) * D_ + d;
#pragma unroll
    for (int j = 0; j < GC; j++) {
        float tx = px[base], txx = pxx[base], to = po[base];
        px[base] = ox; pxx[base] = oxx; po[base] = oo;
        ox += tx; oxx += txx; oo += to;
        base += D_;
    }
}

// K3: per (b, chunk) serial walk over CT timesteps, batched W=4 per
// reduction round (running sums are thread-local; only the 4 gate scalars
// per timestep need cross-thread reduction).
__global__ __launch_bounds__(256) void k3_main(
        const float* __restrict__ x,
        const float* __restrict__ px, const float* __restrict__ pxx,
        const float* __restrict__ po,
        const float* __restrict__ p_log_tau,
        const float* __restrict__ p_log_sigma_raw,
        const float* __restrict__ p_log_w_raw,
        float* __restrict__ y) {
    __shared__ float red[4 * 16];
    __shared__ float gates[4];

    int bid = blockIdx.x;
    int b = bid / NC, c = bid % NC;
    int tid = threadIdx.x;
    int d0 = tid * 8;

    float tau   = __expf(p_log_tau[0]);
    float sigma = log1pf(__expf(p_log_sigma_raw[0]));
    float w     = log1pf(__expf(p_log_w_raw[0]));

    float cx[8], cxx[8], co[8];
    size_t pidx = (size_t)(b * NC + c) * D_ + d0;
    {
        float4 a0 = *(const float4*)(px  + pidx);
        float4 a1 = *(const float4*)(px  + pidx + 4);
        float4 b0 = *(const float4*)(pxx + pidx);
        float4 b1 = *(const float4*)(pxx + pidx + 4);
        float4 c0 = *(const float4*)(po  + pidx);
        float4 c1 = *(const float4*)(po  + pidx + 4);
        cx[0]=a0.x; cx[1]=a0.y; cx[2]=a0.z; cx[3]=a0.w;
        cx[4]=a1.x; cx[5]=a1.y; cx[6]=a1.z; cx[7]=a1.w;
        cxx[0]=b0.x; cxx[1]=b0.y; cxx[2]=b0.z; cxx[3]=b0.w;
        cxx[4]=b1.x; cxx[5]=b1.y; cxx[6]=b1.z; cxx[7]=b1.w;
        co[0]=c0.x; co[1]=c0.y; co[2]=c0.z; co[3]=c0.w;
        co[4]=c1.x; co[5]=c1.y; co[6]=c1.z; co[7]=c1.w;
    }

    const float* xb = x + ((size_t)(b * T_ + c * CT)) * D_ + d0;
    float*       yb = y + ((size_t)(b * T_ + c * CT)) * D_ + d0;

    for (int r = 0; r < CT / 4; r++) {
        float acc[16];
#pragma unroll
        for (int k = 0; k < 16; k++) acc[k] = 0.f;
        float o[4][8];

#pragma unroll
        for (int t = 0; t < 4; t++) {
            int tg = c * CT + r * 4 + t;
            float inv = fast_rcp((float)(tg + 1));
            const float* xr = xb + (size_t)(r * 4 + t) * D_;
            float4 v0 = *(const float4*)(xr);
            float4 v1 = *(const float4*)(xr + 4);
            float v[8] = {v0.x, v0.y, v0.z, v0.w, v1.x, v1.y, v1.z, v1.w};
#pragma unroll
            for (int i = 0; i < 8; i++) {
                float vv = v[i];
                float oo = gelu_tanh(vv);
                o[t][i] = oo;
                float mu = cx[i] * inv;
                float sq = cxx[i] * inv;
                float var = fmaxf(fmaf(-mu, mu, sq), 1e-4f);
                float stde = __builtin_amdgcn_sqrtf(var) + 1e-5f;
                float z = (vv - mu) * fast_rcp(stde);
                acc[t * 4 + 0] += fabsf(z);
                float mo = co[i] * inv;
                acc[t * 4 + 1] = fmaf(oo, mo, acc[t * 4 + 1]);
                acc[t * 4 + 2] = fmaf(oo, oo, acc[t * 4 + 2]);
                acc[t * 4 + 3] = fmaf(mo, mo, acc[t * 4 + 3]);
                cx[i] += vv;
                cxx[i] = fmaf(vv, vv, cxx[i]);
                co[i] += oo;
            }
        }

        // wave reduce: 16 independent chains -> pipelined ds ops
#pragma unroll
        for (int off = 32; off >= 1; off >>= 1) {
#pragma unroll
            for (int k = 0; k < 16; k++) acc[k] += __shfl_down(acc[k], off);
        }

        __syncthreads();   // previous round's red/gates consumers are done
        if ((tid & 63) == 0) {
            int wbase = (tid >> 6) * 16;
#pragma unroll
            for (int k = 0; k < 16; k++) red[wbase + k] = acc[k];
        }
        __syncthreads();
        if (tid < 4) {
            int t = tid;
            float s0 = 0.f, s1 = 0.f, s2 = 0.f, s3 = 0.f;
#pragma unroll
            for (int wv = 0; wv < 4; wv++) {
                s0 += red[wv * 16 + t * 4 + 0];
                s1 += red[wv * 16 + t * 4 + 1];
                s2 += red[wv * 16 + t * 4 + 2];
                s3 += red[wv * 16 + t * 4 + 3];
            }
            int tg = c * CT + r * 4 + t;
            float mask = (tg >= 1) ? 1.0f : 0.0f;
            float mabs = s0 * (1.0f / (float)D_) * mask;
            float denom = fmaxf(sqrtf(s2), 1e-12f) * fmaxf(sqrtf(s3), 1e-12f);
            float cosv = (s1 * fast_rcp(denom)) * mask;
            gates[t] = __expf(-tau * cosv) * (1.0f + w * fast_tanh(sigma * mabs));
        }
        __syncthreads();

#pragma unroll
        for (int t = 0; t < 4; t++) {
            float g = gates[t];
            float* yr = yb + (size_t)(r * 4 + t) * D_;
            *(float4*)(yr)     = make_float4(o[t][0]*g, o[t][1]*g, o[t][2]*g, o[t][3]*g);
            *(float4*)(yr + 4) = make_float4(o[t][4]*g, o[t][5]*g, o[t][6]*g, o[t][7]*g);
        }
    }
}

extern "C" void kernel_launch(void* const* d_in, const int* in_sizes, int n_in,
                              void* d_out, int out_size, void* d_ws, size_t ws_size,
                              hipStream_t stream) {
    const float* x   = (const float*)d_in[0];
    const float* lt  = (const float*)d_in[1];
    const float* lsr = (const float*)d_in[2];
    const float* lwr = (const float*)d_in[3];
    float* y = (float*)d_out;

    const size_t npart = (size_t)B_ * NC * D_;      // 1,048,576 floats each
    const size_t ngrp  = (size_t)B_ * NG * D_;      // 65,536 floats each
    float* px  = (float*)d_ws;
    float* pxx = px  + npart;
    float* po  = pxx + npart;
    float* gx  = po  + npart;
    float* gxx = gx  + ngrp;
    float* go  = gxx + ngrp;
    // total ws: 3*4MiB + 3*256KiB = 12.75 MiB

    k1_partials<<<B_ * NC, 256, 0, stream>>>(x, px, pxx, po);
    k2a_group_sums<<<(B_ * NG * D_) / 256, 256, 0, stream>>>(px, pxx, po, gx, gxx, go);
    k2c_scan<<<(B_ * NG * D_) / 256, 256, 0, stream>>>(px, pxx, po, gx, gxx, go);
    k3_main<<<B_ * NC, 256, 0, stream>>>(x, px, pxx, po, lt, lsr, lwr, y);
}